// Round 7
// baseline (1376.756 us; speedup 1.0000x reference)
//
#include <hip/hip_runtime.h>

typedef unsigned short u16;
typedef short s8v __attribute__((ext_vector_type(8)));
typedef float f4v __attribute__((ext_vector_type(4)));

__device__ __forceinline__ float bf2f(u16 u) {
    union { unsigned int i; float f; } x; x.i = ((unsigned int)u) << 16; return x.f;
}
__device__ __forceinline__ u16 f2bf(float f) {
    union { float f; unsigned int i; } x; x.f = f;
    unsigned int r = x.i + 0x7fffu + ((x.i >> 16) & 1u);
    return (u16)(r >> 16);
}

// ---------------------------------------------------------------------------
// bf16 MFMA GEMM over f32 global inputs: out[M,N] = epi(A @ W + bias), out
// bf16 (ws). A is f32 global (AF32=1) or bf16 ws (AF32=0); W/bias/BN params
// are f32 global. EPI==0: +bias. EPI==1: relu(BN(y+bias)).
// MFMA core + C-layout proven in round 2 (outputs 0,1 passed through it).
// ---------------------------------------------------------------------------
template<int EPI, int AF32>
__global__ __launch_bounds__(256) void gemm_k(
    const void* __restrict__ Av,
    const float* __restrict__ W,
    const float* __restrict__ bias,
    const float* __restrict__ gam, const float* __restrict__ bet,
    const float* __restrict__ rmean, const float* __restrict__ rvar,
    u16* __restrict__ out,
    int M, int N, int K)
{
    const int n0  = blockIdx.x * 64;
    const int m0  = blockIdx.y * 64;
    const int tid = threadIdx.x;
    const int lane = tid & 63;
    const int w    = tid >> 6;
    const int wm   = (w >> 1) * 32;
    const int wn   = (w & 1) * 32;

    __shared__ __align__(16) u16 As[64 * 64];   // As[m][k] bf16
    __shared__ __align__(16) u16 Bs[64 * 64];   // Bs[n][k] bf16 (W^T tile)

    f4v acc[2][2] = {};

    const int arow = tid >> 2;
    const int acol = (tid & 3) << 3;
    const int bn   = tid & 63;
    const int bk0  = (tid >> 6) << 3;
    const int lq = lane >> 4;
    const int lr = lane & 15;

    for (int kk = 0; kk < K; kk += 64) {
        // --- stage A tile (convert f32->bf16 if AF32) ---
        if (AF32) {
            const float* ap = (const float*)Av + (size_t)(m0 + arow) * K + kk;
            #pragma unroll
            for (int h = 0; h < 2; ++h) {
                const int c = acol + h * 32;
                float4 f0 = *(const float4*)(ap + c);
                float4 f1 = *(const float4*)(ap + c + 4);
                s8v v;
                v[0]=(short)f2bf(f0.x); v[1]=(short)f2bf(f0.y);
                v[2]=(short)f2bf(f0.z); v[3]=(short)f2bf(f0.w);
                v[4]=(short)f2bf(f1.x); v[5]=(short)f2bf(f1.y);
                v[6]=(short)f2bf(f1.z); v[7]=(short)f2bf(f1.w);
                *(s8v*)&As[arow * 64 + c] = v;
            }
        } else {
            const u16* ap = (const u16*)Av + (size_t)(m0 + arow) * K + kk;
            *(s8v*)&As[arow * 64 + acol]      = *(const s8v*)(ap + acol);
            *(s8v*)&As[arow * 64 + acol + 32] = *(const s8v*)(ap + acol + 32);
        }
        // --- stage W tile transposed, f32 gather -> bf16 ---
        #pragma unroll
        for (int half = 0; half < 64; half += 32) {
            const float* wp = W + (size_t)(kk + half + bk0) * N + n0 + bn;
            s8v bv;
            #pragma unroll
            for (int j = 0; j < 8; ++j) bv[j] = (short)f2bf(wp[(size_t)j * N]);
            *(s8v*)&Bs[bn * 64 + half + bk0] = bv;
        }
        __syncthreads();
        #pragma unroll
        for (int ks = 0; ks < 64; ks += 32) {
            const int kq = ks + (lq << 3);
            s8v a0 = *(const s8v*)&As[(wm +      lr) * 64 + kq];
            s8v a1 = *(const s8v*)&As[(wm + 16 + lr) * 64 + kq];
            s8v b0 = *(const s8v*)&Bs[(wn +      lr) * 64 + kq];
            s8v b1 = *(const s8v*)&Bs[(wn + 16 + lr) * 64 + kq];
            acc[0][0] = __builtin_amdgcn_mfma_f32_16x16x32_bf16(a0, b0, acc[0][0], 0, 0, 0);
            acc[0][1] = __builtin_amdgcn_mfma_f32_16x16x32_bf16(a0, b1, acc[0][1], 0, 0, 0);
            acc[1][0] = __builtin_amdgcn_mfma_f32_16x16x32_bf16(a1, b0, acc[1][0], 0, 0, 0);
            acc[1][1] = __builtin_amdgcn_mfma_f32_16x16x32_bf16(a1, b1, acc[1][1], 0, 0, 0);
        }
        __syncthreads();
    }

    // epilogue: D[row=(lane>>4)*4+r][col=lane&15] per 16x16 sub-tile
    const int rq = lq << 2;
    #pragma unroll
    for (int j = 0; j < 2; ++j) {
        const int gcol = n0 + wn + j * 16 + lr;
        float scale = 1.f;
        float shift = bias[gcol];
        if (EPI == 1) {
            const float sc = gam[gcol] / sqrtf(rvar[gcol] + 1e-5f);
            scale = sc;
            shift = (shift - rmean[gcol]) * sc + bet[gcol];
        }
        #pragma unroll
        for (int i = 0; i < 2; ++i) {
            const int grow0 = m0 + wm + i * 16 + rq;
            #pragma unroll
            for (int r = 0; r < 4; ++r) {
                float yv = fmaf(acc[i][j][r], scale, shift);
                if (EPI == 1) yv = fmaxf(yv, 0.f);
                out[(size_t)(grow0 + r) * N + gcol] = f2bf(yv);
            }
        }
    }
}

// ---------------------------------------------------------------------------
// f32-exact tiled GEMM + BN + ReLU (routing h1): out = relu(BN(A@W+bias)),
// all f32. 64x64 tile, 256 threads, 4x4 outputs/thread.
// ---------------------------------------------------------------------------
__global__ __launch_bounds__(256) void gemm_f32bn_k(
    const float* __restrict__ A, const float* __restrict__ W,
    const float* __restrict__ bias, const float* __restrict__ g,
    const float* __restrict__ be, const float* __restrict__ m,
    const float* __restrict__ v, float* __restrict__ out,
    int M, int N, int K)
{
    const int n0 = blockIdx.x * 64, m0 = blockIdx.y * 64;
    const int tid = threadIdx.x;
    const int tx = tid & 15, ty = tid >> 4;
    __shared__ float As[64][65];
    __shared__ float Bs[64][64];
    float acc[4][4] = {};
    const int sr = tid >> 2;
    const int sc = (tid & 3) << 4;
    for (int kk = 0; kk < K; kk += 64) {
        const float* ap = A + (size_t)(m0 + sr) * K + kk + sc;
        #pragma unroll
        for (int q = 0; q < 4; ++q) {
            float4 f = *(const float4*)(ap + q * 4);
            As[sr][sc + q*4 + 0] = f.x; As[sr][sc + q*4 + 1] = f.y;
            As[sr][sc + q*4 + 2] = f.z; As[sr][sc + q*4 + 3] = f.w;
        }
        const float* wp = W + (size_t)(kk + sr) * N + n0 + sc;
        #pragma unroll
        for (int q = 0; q < 4; ++q)
            *(float4*)&Bs[sr][sc + q*4] = *(const float4*)(wp + q * 4);
        __syncthreads();
        #pragma unroll 4
        for (int kq = 0; kq < 64; ++kq) {
            float a[4], bv[4];
            #pragma unroll
            for (int i = 0; i < 4; ++i) a[i] = As[ty*4 + i][kq];
            #pragma unroll
            for (int j = 0; j < 4; ++j) bv[j] = Bs[kq][tx*4 + j];
            #pragma unroll
            for (int i = 0; i < 4; ++i)
                #pragma unroll
                for (int j = 0; j < 4; ++j)
                    acc[i][j] = fmaf(a[i], bv[j], acc[i][j]);
        }
        __syncthreads();
    }
    #pragma unroll
    for (int j = 0; j < 4; ++j) {
        const int c = n0 + tx*4 + j;
        const float scv = g[c] / sqrtf(v[c] + 1e-5f);
        const float sh  = (bias[c] - m[c]) * scv + be[c];
        #pragma unroll
        for (int i = 0; i < 4; ++i) {
            const int r = m0 + ty*4 + i;
            out[(size_t)r * N + c] = fmaxf(fmaf(acc[i][j], scv, sh), 0.f);
        }
    }
}

// ---------------------------------------------------------------------------
// Fused routing tail (all f32): h2 = relu(BN2(h1 @ bw2 + bb2));
// logits = h2 @ cw + cb ; out_src = log_softmax ; label = argmax.
// One block (256 threads) per batch row.
// ---------------------------------------------------------------------------
__global__ __launch_bounds__(256) void h2cls_k(
    const float* __restrict__ h1,
    const float* __restrict__ bw2, const float* __restrict__ bb2,
    const float* __restrict__ bg2, const float* __restrict__ bbe2,
    const float* __restrict__ bm2, const float* __restrict__ bv2,
    const float* __restrict__ cw,  const float* __restrict__ cb,
    float* __restrict__ out_src, int* __restrict__ label)
{
    const int b = blockIdx.x;
    const int t = threadIdx.x;
    __shared__ float h1s[512];
    __shared__ float h2s[256];

    h1s[t]       = h1[(size_t)b * 512 + t];
    h1s[t + 256] = h1[(size_t)b * 512 + t + 256];
    __syncthreads();

    float acc = 0.f;
    #pragma unroll 8
    for (int k = 0; k < 512; ++k)
        acc = fmaf(h1s[k], bw2[(size_t)k * 256 + t], acc);

    const float sc = bg2[t] / sqrtf(bv2[t] + 1e-5f);
    const float hv = (acc + bb2[t] - bm2[t]) * sc + bbe2[t];
    h2s[t] = fmaxf(hv, 0.f);
    __syncthreads();

    if (t < 64) {
        float p[8] = {};
        for (int k = t; k < 256; k += 64) {
            const float x = h2s[k];
            #pragma unroll
            for (int c = 0; c < 8; ++c) p[c] = fmaf(x, cw[k * 8 + c], p[c]);
        }
        #pragma unroll
        for (int off = 32; off; off >>= 1)
            #pragma unroll
            for (int c = 0; c < 8; ++c) p[c] += __shfl_xor(p[c], off, 64);
        if (t == 0) {
            float lg[8];
            #pragma unroll
            for (int c = 0; c < 8; ++c) lg[c] = p[c] + cb[c];
            float mx = lg[0]; int am = 0;
            #pragma unroll
            for (int c = 1; c < 8; ++c) if (lg[c] > mx) { mx = lg[c]; am = c; }
            float ssum = 0.f;
            #pragma unroll
            for (int c = 0; c < 8; ++c) ssum += expf(lg[c] - mx);
            const float lse = mx + logf(ssum);
            #pragma unroll
            for (int c = 0; c < 8; ++c) out_src[b * 8 + c] = lg[c] - lse;
            label[b] = am;
        }
    }
}

// ---------------------------------------------------------------------------
// In-place LayerNorm + ReLU over bf16 rows of length N; gamma/beta f32.
// ---------------------------------------------------------------------------
template<int N>
__global__ __launch_bounds__(256) void ln_relu_k(u16* __restrict__ Y,
        const float* __restrict__ g, const float* __restrict__ bb)
{
    const int b = blockIdx.x;
    u16* y = Y + (size_t)b * N;
    const int tid = threadIdx.x;
    constexpr int CNT = N >> 8;
    float vals[CNT];
    float s = 0.f, sq = 0.f;
    #pragma unroll
    for (int i = 0; i < CNT; ++i) {
        float xv = bf2f(y[tid + (i << 8)]);
        vals[i] = xv; s += xv; sq += xv * xv;
    }
    #pragma unroll
    for (int off = 32; off; off >>= 1) {
        s  += __shfl_xor(s,  off, 64);
        sq += __shfl_xor(sq, off, 64);
    }
    __shared__ float rs[4], rq[4];
    if ((tid & 63) == 0) { rs[tid >> 6] = s; rq[tid >> 6] = sq; }
    __syncthreads();
    s  = rs[0] + rs[1] + rs[2] + rs[3];
    sq = rq[0] + rq[1] + rq[2] + rq[3];
    const float inv = 1.f / (float)N;
    const float mu  = s * inv;
    const float var = sq * inv - mu * mu;
    const float rstd = rsqrtf(var + 1e-5f);
    #pragma unroll
    for (int i = 0; i < CNT; ++i) {
        const int idx = tid + (i << 8);
        float o = (vals[i] - mu) * rstd * g[idx] + bb[idx];
        y[idx] = f2bf(fmaxf(o, 0.f));
    }
}

// ---------------------------------------------------------------------------
// 2-class head + log_softmax: X bf16 (ws), W/bias f32, out f32. 1 wave/row.
// ---------------------------------------------------------------------------
__global__ __launch_bounds__(64) void head2_k(const u16* __restrict__ X,
        const float* __restrict__ W, const float* __restrict__ bias,
        int K, float* __restrict__ out)
{
    const int b = blockIdx.x;
    const int lane = threadIdx.x;
    const u16* x = X + (size_t)b * K;
    float p0 = 0.f, p1 = 0.f;
    for (int k = lane; k < K; k += 64) {
        const float xv = bf2f(x[k]);
        p0 = fmaf(xv, W[k * 2],     p0);
        p1 = fmaf(xv, W[k * 2 + 1], p1);
    }
    #pragma unroll
    for (int off = 32; off; off >>= 1) {
        p0 += __shfl_xor(p0, off, 64);
        p1 += __shfl_xor(p1, off, 64);
    }
    if (lane == 0) {
        const float l0 = p0 + bias[0];
        const float l1 = p1 + bias[1];
        const float mx = fmaxf(l0, l1);
        const float lse = mx + logf(expf(l0 - mx) + expf(l1 - mx));
        out[b * 2]     = l0 - lse;
        out[b * 2 + 1] = l1 - lse;
    }
}

// ---------------------------------------------------------------------------
// sout gather: out[b][:] = eo[label[b]][b][:]   (eo f32 [E][B][2])
// ---------------------------------------------------------------------------
__global__ __launch_bounds__(256) void gather_k(const float* __restrict__ eo,
        const int* __restrict__ label, float* __restrict__ out, int B)
{
    const int b = blockIdx.x * 256 + threadIdx.x;
    if (b >= B) return;
    const int e = label[b];
    out[b * 2]     = eo[((size_t)e * B + b) * 2];
    out[b * 2 + 1] = eo[((size_t)e * B + b) * 2 + 1];
}

__global__ __launch_bounds__(256) void copy16_k(const uint4* __restrict__ in,
                                                uint4* __restrict__ out, int n16)
{
    const int i = blockIdx.x * blockDim.x + threadIdx.x;
    if (i < n16) out[i] = in[i];
}

// ---------------------------------------------------------------------------

extern "C" void kernel_launch(void* const* d_in, const int* in_sizes, int n_in,
                              void* d_out, int out_size, void* d_ws, size_t ws_size,
                              hipStream_t stream)
{
    const int B = 2048, D = 1280, E = 8;

    // ALL inputs are float32 (established round 7: the round-2 pass occurred
    // with the adaptive kernel's f32 branch; every bf16-interpreting round
    // NaN'd instantly via rsqrt(negative bv1-garbage)).
    const float* src = (const float*)d_in[0];
    const float *bw1 = (const float*)d_in[1],  *bb1 = (const float*)d_in[2],
                *bg1 = (const float*)d_in[3],  *bbe1 = (const float*)d_in[4],
                *bm1 = (const float*)d_in[5],  *bv1 = (const float*)d_in[6];
    const float *bw2 = (const float*)d_in[7],  *bb2 = (const float*)d_in[8],
                *bg2 = (const float*)d_in[9],  *bbe2 = (const float*)d_in[10],
                *bm2 = (const float*)d_in[11], *bv2 = (const float*)d_in[12];
    const float *cw  = (const float*)d_in[13], *cb  = (const float*)d_in[14];
    const float *dw1 = (const float*)d_in[15], *db1 = (const float*)d_in[16],
                *dg1 = (const float*)d_in[17], *dbe1 = (const float*)d_in[18],
                *dm1 = (const float*)d_in[19], *dv1 = (const float*)d_in[20];
    const float *dw2 = (const float*)d_in[21], *db2 = (const float*)d_in[22],
                *dg2 = (const float*)d_in[23], *dbe2 = (const float*)d_in[24],
                *dm2 = (const float*)d_in[25], *dv2 = (const float*)d_in[26];
    const float *dw3 = (const float*)d_in[27], *db3 = (const float*)d_in[28],
                *dg3 = (const float*)d_in[29], *dbe3 = (const float*)d_in[30],
                *dm3 = (const float*)d_in[31], *dv3 = (const float*)d_in[32];
    const float *dw4 = (const float*)d_in[33], *db4 = (const float*)d_in[34];
    const float *ew1 = (const float*)d_in[35], *eb1 = (const float*)d_in[36],
                *eg1 = (const float*)d_in[37], *ebe1 = (const float*)d_in[38];
    const float *ew2 = (const float*)d_in[39], *eb2 = (const float*)d_in[40],
                *eg2 = (const float*)d_in[41], *ebe2 = (const float*)d_in[42];
    const float *ew3 = (const float*)d_in[43], *eb3 = (const float*)d_in[44],
                *eg3 = (const float*)d_in[45], *ebe3 = (const float*)d_in[46];
    const float *ew4 = (const float*)d_in[47], *eb4 = (const float*)d_in[48];

    // outputs (float32): src[B,8] | dclf[B,2] | sout[B,2] | share[B,D]
    float* out_src   = (float*)d_out;
    float* out_dclf  = out_src + B * E;
    float* out_sout  = out_dclf + B * 2;
    float* out_share = out_sout + B * 2;

    // ws (12.72 MB total, all within the empirically-functional low range):
    //   xa  [0, 4M)      bf16 [2048][1024] act ping (experts; dd1/dd3 later)
    //   xb  [4M, 8M)     bf16 [2048][1024] act pong (experts; dd2 later)
    //   h1  [8M, 12M)    f32  [2048][512]  routing hidden
    //   eo  [12M, +128K) f32  [8][2048][2]
    //   label [12M+128K, +8K)
    char* ws = (char*)d_ws;
    u16*   xa = (u16*)ws;
    u16*   xb = (u16*)(ws + 4194304);
    float* h1 = (float*)(ws + 8388608);
    float* eo = (float*)(ws + 12582912);
    int* label = (int*)(ws + 12714 * 1024);   // 12582912+131072 = 13019136? no:
    label = (int*)(ws + 12582912 + 131072);

    // share passthrough (f32 bytes)
    copy16_k<<<dim3((B * D * 4 / 16 + 255) / 256), 256, 0, stream>>>(
        (const uint4*)src, (uint4*)out_share, B * D * 4 / 16);

    // ---- routing: f32-exact h1 GEMM + fused h2/classifier ----
    gemm_f32bn_k<<<dim3(512 / 64, B / 64), 256, 0, stream>>>(
        src, bw1, bb1, bg1, bbe1, bm1, bv1, h1, B, 512, D);
    h2cls_k<<<dim3(B), 256, 0, stream>>>(
        h1, bw2, bb2, bg2, bbe2, bm2, bv2, cw, cb, out_src, label);

    // ---- experts, one at a time (bf16 MFMA internal, f32 boundaries) ----
    for (int e = 0; e < E; ++e) {
        gemm_k<0, 1><<<dim3(1024 / 64, B / 64), 256, 0, stream>>>(
            src, ew1 + (size_t)e * D * 1024, eb1 + (size_t)e * 1024,
            nullptr, nullptr, nullptr, nullptr, xa, B, 1024, D);
        ln_relu_k<1024><<<dim3(B), 256, 0, stream>>>(
            xa, eg1 + (size_t)e * 1024, ebe1 + (size_t)e * 1024);

        gemm_k<0, 0><<<dim3(1024 / 64, B / 64), 256, 0, stream>>>(
            xa, ew2 + (size_t)e * 1024 * 1024, eb2 + (size_t)e * 1024,
            nullptr, nullptr, nullptr, nullptr, xb, B, 1024, 1024);
        ln_relu_k<1024><<<dim3(B), 256, 0, stream>>>(
            xb, eg2 + (size_t)e * 1024, ebe2 + (size_t)e * 1024);

        gemm_k<0, 0><<<dim3(512 / 64, B / 64), 256, 0, stream>>>(
            xb, ew3 + (size_t)e * 1024 * 512, eb3 + (size_t)e * 512,
            nullptr, nullptr, nullptr, nullptr, xa, B, 512, 1024);
        ln_relu_k<512><<<dim3(B), 256, 0, stream>>>(
            xa, eg3 + (size_t)e * 512, ebe3 + (size_t)e * 512);

        head2_k<<<dim3(B), 64, 0, stream>>>(
            xa, ew4 + (size_t)e * 512 * 2, eb4 + (size_t)e * 2, 512,
            eo + (size_t)e * B * 2);
    }

    // sout gather (label from h2cls_k, eo from expert loop)
    gather_k<<<dim3(B / 256), 256, 0, stream>>>(eo, label, out_sout, B);

    // ---- domain classifier (bf16 MFMA internal, reuses xa/xb) ----
    gemm_k<1, 1><<<dim3(1024 / 64, B / 64), 256, 0, stream>>>(
        src, dw1, db1, dg1, dbe1, dm1, dv1, xa, B, 1024, D);
    gemm_k<1, 0><<<dim3(1024 / 64, B / 64), 256, 0, stream>>>(
        xa, dw2, db2, dg2, dbe2, dm2, dv2, xb, B, 1024, 1024);
    gemm_k<1, 0><<<dim3(512 / 64, B / 64), 256, 0, stream>>>(
        xb, dw3, db3, dg3, dbe3, dm3, dv3, xa, B, 512, 1024);
    head2_k<<<dim3(B), 64, 0, stream>>>(xa, dw4, db4, 512, out_dclf);
}

// Round 8
// 1152.411 us; speedup vs baseline: 1.1947x; 1.1947x over previous
//
#include <hip/hip_runtime.h>

typedef unsigned short u16;
typedef short s8v __attribute__((ext_vector_type(8)));
typedef float f4v __attribute__((ext_vector_type(4)));

__device__ __forceinline__ float bf2f(u16 u) {
    union { unsigned int i; float f; } x; x.i = ((unsigned int)u) << 16; return x.f;
}
__device__ __forceinline__ u16 f2bf(float f) {
    union { float f; unsigned int i; } x; x.f = f;
    unsigned int r = x.i + 0x7fffu + ((x.i >> 16) & 1u);
    return (u16)(r >> 16);
}

// ---------------------------------------------------------------------------
// Weight convert+transpose: W f32 [K][N] -> WT bf16 [N][K]. Batched over z.
// 64x64 LDS tile; reads and writes both coalesced. K,N multiples of 64.
// ---------------------------------------------------------------------------
__global__ __launch_bounds__(256) void convT_k(const float* __restrict__ W,
        u16* __restrict__ WT, int N, int K)
{
    const size_t mat = (size_t)blockIdx.z * K * N;
    const int n0 = blockIdx.x * 64, k0 = blockIdx.y * 64;
    __shared__ float t[64][65];
    const int r = threadIdx.x >> 2;          // 0..63
    const int c = (threadIdx.x & 3) << 4;    // 0,16,32,48
    const float* wp = W + mat + (size_t)(k0 + r) * N + n0 + c;
    #pragma unroll
    for (int q = 0; q < 16; q += 4) {
        float4 f = *(const float4*)(wp + q);
        t[c + q + 0][r] = f.x; t[c + q + 1][r] = f.y;
        t[c + q + 2][r] = f.z; t[c + q + 3][r] = f.w;
    }
    __syncthreads();
    u16* op = WT + mat + (size_t)(n0 + r) * K + k0 + c;
    #pragma unroll
    for (int q = 0; q < 16; q += 8) {
        s8v v;
        #pragma unroll
        for (int j = 0; j < 8; ++j) v[j] = (short)f2bf(t[r][c + q + j]);
        *(s8v*)(op + q) = v;
    }
}

// ---------------------------------------------------------------------------
// Elementwise f32 -> bf16 (8 per thread). n8 = elems/8.
// ---------------------------------------------------------------------------
__global__ __launch_bounds__(256) void conv_k(const float* __restrict__ in,
        u16* __restrict__ out, int n8)
{
    const int i = blockIdx.x * 256 + threadIdx.x;
    if (i >= n8) return;
    const float4 f0 = ((const float4*)in)[i * 2];
    const float4 f1 = ((const float4*)in)[i * 2 + 1];
    s8v v;
    v[0]=(short)f2bf(f0.x); v[1]=(short)f2bf(f0.y);
    v[2]=(short)f2bf(f0.z); v[3]=(short)f2bf(f0.w);
    v[4]=(short)f2bf(f1.x); v[5]=(short)f2bf(f1.y);
    v[6]=(short)f2bf(f1.z); v[7]=(short)f2bf(f1.w);
    ((s8v*)out)[i] = v;
}

// ---------------------------------------------------------------------------
// Pure-bf16 MFMA GEMM with transposed W: out[M,N] = epi(A @ WT^T + bias).
// A bf16 [M][K], WT bf16 [N][K] -> both staged with identical k-contiguous
// 16B vector loads (m92 pattern). EPI 0: +bias(f32). EPI 1: relu(BN(f32)).
// ---------------------------------------------------------------------------
template<int EPI>
__global__ __launch_bounds__(256) void gemm_bt_k(
    const u16* __restrict__ A,
    const u16* __restrict__ WT,
    const float* __restrict__ bias,
    const float* __restrict__ gam, const float* __restrict__ bet,
    const float* __restrict__ rmean, const float* __restrict__ rvar,
    u16* __restrict__ out, int M, int N, int K)
{
    const int n0  = blockIdx.x * 64;
    const int m0  = blockIdx.y * 64;
    const int tid = threadIdx.x;
    const int lane = tid & 63;
    const int w    = tid >> 6;
    const int wm   = (w >> 1) * 32;
    const int wn   = (w & 1) * 32;

    __shared__ __align__(16) u16 As[64 * 64];   // As[m][k]
    __shared__ __align__(16) u16 Bs[64 * 64];   // Bs[n][k]

    f4v acc[2][2] = {};

    const int row  = tid >> 2;          // 0..63
    const int col8 = (tid & 3) << 3;    // 0,8,16,24
    const int lq = lane >> 4, lr = lane & 15;

    const u16* ap = A  + (size_t)(m0 + row) * K + col8;
    const u16* bp = WT + (size_t)(n0 + row) * K + col8;

    for (int kk = 0; kk < K; kk += 64) {
        *(s8v*)&As[row * 64 + col8]      = *(const s8v*)(ap + kk);
        *(s8v*)&As[row * 64 + col8 + 32] = *(const s8v*)(ap + kk + 32);
        *(s8v*)&Bs[row * 64 + col8]      = *(const s8v*)(bp + kk);
        *(s8v*)&Bs[row * 64 + col8 + 32] = *(const s8v*)(bp + kk + 32);
        __syncthreads();
        #pragma unroll
        for (int ks = 0; ks < 64; ks += 32) {
            const int kq = ks + (lq << 3);
            s8v a0 = *(const s8v*)&As[(wm +      lr) * 64 + kq];
            s8v a1 = *(const s8v*)&As[(wm + 16 + lr) * 64 + kq];
            s8v b0 = *(const s8v*)&Bs[(wn +      lr) * 64 + kq];
            s8v b1 = *(const s8v*)&Bs[(wn + 16 + lr) * 64 + kq];
            acc[0][0] = __builtin_amdgcn_mfma_f32_16x16x32_bf16(a0, b0, acc[0][0], 0, 0, 0);
            acc[0][1] = __builtin_amdgcn_mfma_f32_16x16x32_bf16(a0, b1, acc[0][1], 0, 0, 0);
            acc[1][0] = __builtin_amdgcn_mfma_f32_16x16x32_bf16(a1, b0, acc[1][0], 0, 0, 0);
            acc[1][1] = __builtin_amdgcn_mfma_f32_16x16x32_bf16(a1, b1, acc[1][1], 0, 0, 0);
        }
        __syncthreads();
    }

    // epilogue: D[row=(lane>>4)*4+r][col=lane&15] per 16x16 sub-tile
    const int rq = lq << 2;
    #pragma unroll
    for (int j = 0; j < 2; ++j) {
        const int gcol = n0 + wn + j * 16 + lr;
        float scale = 1.f;
        float shift = bias[gcol];
        if (EPI == 1) {
            const float sc = gam[gcol] / sqrtf(rvar[gcol] + 1e-5f);
            scale = sc;
            shift = (shift - rmean[gcol]) * sc + bet[gcol];
        }
        #pragma unroll
        for (int i = 0; i < 2; ++i) {
            const int grow0 = m0 + wm + i * 16 + rq;
            #pragma unroll
            for (int r = 0; r < 4; ++r) {
                float yv = fmaf(acc[i][j][r], scale, shift);
                if (EPI == 1) yv = fmaxf(yv, 0.f);
                out[(size_t)(grow0 + r) * N + gcol] = f2bf(yv);
            }
        }
    }
}

// ---------------------------------------------------------------------------
// f32-exact tiled GEMM + BN + ReLU (routing h1) — unchanged from round 7.
// ---------------------------------------------------------------------------
__global__ __launch_bounds__(256) void gemm_f32bn_k(
    const float* __restrict__ A, const float* __restrict__ W,
    const float* __restrict__ bias, const float* __restrict__ g,
    const float* __restrict__ be, const float* __restrict__ m,
    const float* __restrict__ v, float* __restrict__ out,
    int M, int N, int K)
{
    const int n0 = blockIdx.x * 64, m0 = blockIdx.y * 64;
    const int tid = threadIdx.x;
    const int tx = tid & 15, ty = tid >> 4;
    __shared__ float As[64][65];
    __shared__ float Bs[64][64];
    float acc[4][4] = {};
    const int sr = tid >> 2;
    const int sc = (tid & 3) << 4;
    for (int kk = 0; kk < K; kk += 64) {
        const float* ap = A + (size_t)(m0 + sr) * K + kk + sc;
        #pragma unroll
        for (int q = 0; q < 4; ++q) {
            float4 f = *(const float4*)(ap + q * 4);
            As[sr][sc + q*4 + 0] = f.x; As[sr][sc + q*4 + 1] = f.y;
            As[sr][sc + q*4 + 2] = f.z; As[sr][sc + q*4 + 3] = f.w;
        }
        const float* wp = W + (size_t)(kk + sr) * N + n0 + sc;
        #pragma unroll
        for (int q = 0; q < 4; ++q)
            *(float4*)&Bs[sr][sc + q*4] = *(const float4*)(wp + q * 4);
        __syncthreads();
        #pragma unroll 4
        for (int kq = 0; kq < 64; ++kq) {
            float a[4], bv[4];
            #pragma unroll
            for (int i = 0; i < 4; ++i) a[i] = As[ty*4 + i][kq];
            #pragma unroll
            for (int j = 0; j < 4; ++j) bv[j] = Bs[kq][tx*4 + j];
            #pragma unroll
            for (int i = 0; i < 4; ++i)
                #pragma unroll
                for (int j = 0; j < 4; ++j)
                    acc[i][j] = fmaf(a[i], bv[j], acc[i][j]);
        }
        __syncthreads();
    }
    #pragma unroll
    for (int j = 0; j < 4; ++j) {
        const int c = n0 + tx*4 + j;
        const float scv = g[c] / sqrtf(v[c] + 1e-5f);
        const float sh  = (bias[c] - m[c]) * scv + be[c];
        #pragma unroll
        for (int i = 0; i < 4; ++i) {
            const int r = m0 + ty*4 + i;
            out[(size_t)r * N + c] = fmaxf(fmaf(acc[i][j], scv, sh), 0.f);
        }
    }
}

// ---------------------------------------------------------------------------
// Fused routing tail (all f32) — unchanged from round 7.
// ---------------------------------------------------------------------------
__global__ __launch_bounds__(256) void h2cls_k(
    const float* __restrict__ h1,
    const float* __restrict__ bw2, const float* __restrict__ bb2,
    const float* __restrict__ bg2, const float* __restrict__ bbe2,
    const float* __restrict__ bm2, const float* __restrict__ bv2,
    const float* __restrict__ cw,  const float* __restrict__ cb,
    float* __restrict__ out_src, int* __restrict__ label)
{
    const int b = blockIdx.x;
    const int t = threadIdx.x;
    __shared__ float h1s[512];
    __shared__ float h2s[256];

    h1s[t]       = h1[(size_t)b * 512 + t];
    h1s[t + 256] = h1[(size_t)b * 512 + t + 256];
    __syncthreads();

    float acc = 0.f;
    #pragma unroll 8
    for (int k = 0; k < 512; ++k)
        acc = fmaf(h1s[k], bw2[(size_t)k * 256 + t], acc);

    const float sc = bg2[t] / sqrtf(bv2[t] + 1e-5f);
    const float hv = (acc + bb2[t] - bm2[t]) * sc + bbe2[t];
    h2s[t] = fmaxf(hv, 0.f);
    __syncthreads();

    if (t < 64) {
        float p[8] = {};
        for (int k = t; k < 256; k += 64) {
            const float x = h2s[k];
            #pragma unroll
            for (int c = 0; c < 8; ++c) p[c] = fmaf(x, cw[k * 8 + c], p[c]);
        }
        #pragma unroll
        for (int off = 32; off; off >>= 1)
            #pragma unroll
            for (int c = 0; c < 8; ++c) p[c] += __shfl_xor(p[c], off, 64);
        if (t == 0) {
            float lg[8];
            #pragma unroll
            for (int c = 0; c < 8; ++c) lg[c] = p[c] + cb[c];
            float mx = lg[0]; int am = 0;
            #pragma unroll
            for (int c = 1; c < 8; ++c) if (lg[c] > mx) { mx = lg[c]; am = c; }
            float ssum = 0.f;
            #pragma unroll
            for (int c = 0; c < 8; ++c) ssum += expf(lg[c] - mx);
            const float lse = mx + logf(ssum);
            #pragma unroll
            for (int c = 0; c < 8; ++c) out_src[b * 8 + c] = lg[c] - lse;
            label[b] = am;
        }
    }
}

// ---------------------------------------------------------------------------
// In-place LayerNorm + ReLU, vectorized (ushort4/float4). N in {512,1024}.
// ---------------------------------------------------------------------------
template<int N>
__global__ __launch_bounds__(256) void ln_relu_k(u16* __restrict__ Y,
        const float* __restrict__ g, const float* __restrict__ bb)
{
    const int b = blockIdx.x;
    u16* y = Y + (size_t)b * N;
    const int t = threadIdx.x;
    constexpr int C = N >> 8;   // 4 or 2
    float vals[C];
    if (C == 4) {
        ushort4 u = ((const ushort4*)y)[t];
        vals[0] = bf2f(u.x); vals[1] = bf2f(u.y);
        vals[2] = bf2f(u.z); vals[3] = bf2f(u.w);
    } else {
        ushort2 u = ((const ushort2*)y)[t];
        vals[0] = bf2f(u.x); vals[1] = bf2f(u.y);
    }
    float s = 0.f, sq = 0.f;
    #pragma unroll
    for (int i = 0; i < C; ++i) { s += vals[i]; sq += vals[i] * vals[i]; }
    #pragma unroll
    for (int off = 32; off; off >>= 1) {
        s  += __shfl_xor(s,  off, 64);
        sq += __shfl_xor(sq, off, 64);
    }
    __shared__ float rs[4], rq[4];
    if ((t & 63) == 0) { rs[t >> 6] = s; rq[t >> 6] = sq; }
    __syncthreads();
    s  = rs[0] + rs[1] + rs[2] + rs[3];
    sq = rq[0] + rq[1] + rq[2] + rq[3];
    const float inv = 1.f / (float)N;
    const float mu  = s * inv;
    const float var = sq * inv - mu * mu;
    const float rstd = rsqrtf(var + 1e-5f);
    if (C == 4) {
        float4 gv = ((const float4*)g)[t];
        float4 bv = ((const float4*)bb)[t];
        ushort4 o;
        o.x = f2bf(fmaxf((vals[0] - mu) * rstd * gv.x + bv.x, 0.f));
        o.y = f2bf(fmaxf((vals[1] - mu) * rstd * gv.y + bv.y, 0.f));
        o.z = f2bf(fmaxf((vals[2] - mu) * rstd * gv.z + bv.z, 0.f));
        o.w = f2bf(fmaxf((vals[3] - mu) * rstd * gv.w + bv.w, 0.f));
        ((ushort4*)y)[t] = o;
    } else {
        float2 gv = ((const float2*)g)[t];
        float2 bv = ((const float2*)bb)[t];
        ushort2 o;
        o.x = f2bf(fmaxf((vals[0] - mu) * rstd * gv.x + bv.x, 0.f));
        o.y = f2bf(fmaxf((vals[1] - mu) * rstd * gv.y + bv.y, 0.f));
        ((ushort2*)y)[t] = o;
    }
}

// ---------------------------------------------------------------------------
// 2-class head + log_softmax: X bf16 (ws), W/bias f32, out f32. 1 wave/row.
// ---------------------------------------------------------------------------
__global__ __launch_bounds__(64) void head2_k(const u16* __restrict__ X,
        const float* __restrict__ W, const float* __restrict__ bias,
        int K, float* __restrict__ out)
{
    const int b = blockIdx.x;
    const int lane = threadIdx.x;
    const u16* x = X + (size_t)b * K;
    float p0 = 0.f, p1 = 0.f;
    for (int k = lane; k < K; k += 64) {
        const float xv = bf2f(x[k]);
        p0 = fmaf(xv, W[k * 2],     p0);
        p1 = fmaf(xv, W[k * 2 + 1], p1);
    }
    #pragma unroll
    for (int off = 32; off; off >>= 1) {
        p0 += __shfl_xor(p0, off, 64);
        p1 += __shfl_xor(p1, off, 64);
    }
    if (lane == 0) {
        const float l0 = p0 + bias[0];
        const float l1 = p1 + bias[1];
        const float mx = fmaxf(l0, l1);
        const float lse = mx + logf(expf(l0 - mx) + expf(l1 - mx));
        out[b * 2]     = l0 - lse;
        out[b * 2 + 1] = l1 - lse;
    }
}

__global__ __launch_bounds__(256) void gather_k(const float* __restrict__ eo,
        const int* __restrict__ label, float* __restrict__ out, int B)
{
    const int b = blockIdx.x * 256 + threadIdx.x;
    if (b >= B) return;
    const int e = label[b];
    out[b * 2]     = eo[((size_t)e * B + b) * 2];
    out[b * 2 + 1] = eo[((size_t)e * B + b) * 2 + 1];
}

__global__ __launch_bounds__(256) void copy16_k(const uint4* __restrict__ in,
                                                uint4* __restrict__ out, int n16)
{
    const int i = blockIdx.x * blockDim.x + threadIdx.x;
    if (i < n16) out[i] = in[i];
}

// ---------------------------------------------------------------------------

extern "C" void kernel_launch(void* const* d_in, const int* in_sizes, int n_in,
                              void* d_out, int out_size, void* d_ws, size_t ws_size,
                              hipStream_t stream)
{
    const int B = 2048, D = 1280, E = 8;

    // All inputs float32 (proven round 7).
    const float* src = (const float*)d_in[0];
    const float *bw1 = (const float*)d_in[1],  *bb1 = (const float*)d_in[2],
                *bg1 = (const float*)d_in[3],  *bbe1 = (const float*)d_in[4],
                *bm1 = (const float*)d_in[5],  *bv1 = (const float*)d_in[6];
    const float *bw2 = (const float*)d_in[7],  *bb2 = (const float*)d_in[8],
                *bg2 = (const float*)d_in[9],  *bbe2 = (const float*)d_in[10],
                *bm2 = (const float*)d_in[11], *bv2 = (const float*)d_in[12];
    const float *cw  = (const float*)d_in[13], *cb  = (const float*)d_in[14];
    const float *dw1 = (const float*)d_in[15], *db1 = (const float*)d_in[16],
                *dg1 = (const float*)d_in[17], *dbe1 = (const float*)d_in[18],
                *dm1 = (const float*)d_in[19], *dv1 = (const float*)d_in[20];
    const float *dw2 = (const float*)d_in[21], *db2 = (const float*)d_in[22],
                *dg2 = (const float*)d_in[23], *dbe2 = (const float*)d_in[24],
                *dm2 = (const float*)d_in[25], *dv2 = (const float*)d_in[26];
    const float *dw3 = (const float*)d_in[27], *db3 = (const float*)d_in[28],
                *dg3 = (const float*)d_in[29], *dbe3 = (const float*)d_in[30],
                *dm3 = (const float*)d_in[31], *dv3 = (const float*)d_in[32];
    const float *dw4 = (const float*)d_in[33], *db4 = (const float*)d_in[34];
    const float *ew1 = (const float*)d_in[35], *eb1 = (const float*)d_in[36],
                *eg1 = (const float*)d_in[37], *ebe1 = (const float*)d_in[38];
    const float *ew2 = (const float*)d_in[39], *eb2 = (const float*)d_in[40],
                *eg2 = (const float*)d_in[41], *ebe2 = (const float*)d_in[42];
    const float *ew3 = (const float*)d_in[43], *eb3 = (const float*)d_in[44],
                *eg3 = (const float*)d_in[45], *ebe3 = (const float*)d_in[46];
    const float *ew4 = (const float*)d_in[47], *eb4 = (const float*)d_in[48];

    // outputs (float32): src[B,8] | dclf[B,2] | sout[B,2] | share[B,D]
    float* out_src   = (float*)d_out;
    float* out_dclf  = out_src + B * E;
    float* out_sout  = out_dclf + B * 2;
    float* out_share = out_sout + B * 2;

    // ws layout (65.7 MB total; ws >= 64MiB+12KB proven by round 2):
    //   wT1  [0, 20.97M)          bf16 [8][1024][1280]  ew1^T
    //   wT2  [20.97M, 37.75M)     bf16 [8][1024][1024]  ew2^T
    //   wT3  [37.75M, 46.14M)     bf16 [8][512][1024]   ew3^T
    //   dT1  [46.14M, 48.76M)     bf16 [1024][1280]     dw1^T
    //   dT2  [48.76M, 50.86M)     bf16 [1024][1024]     dw2^T
    //   dT3  [50.86M, 51.90M)     bf16 [512][1024]      dw3^T
    //   srcb [51.90M, 57.15M)     bf16 [2048][1280]
    //   act_a[57.15M, 61.34M)     bf16 [2048][1024]  (h1 f32 lives here first)
    //   act_b[61.34M, 65.54M)     bf16 [2048][1024]
    //   eo   [65.54M, +128K) ; label [+8K)
    char* ws = (char*)d_ws;
    u16*   wT1  = (u16*)(ws);
    u16*   wT2  = (u16*)(ws + 20971520);
    u16*   wT3  = (u16*)(ws + 37748736);
    u16*   dT1  = (u16*)(ws + 46137344);
    u16*   dT2  = (u16*)(ws + 48758784);
    u16*   dT3  = (u16*)(ws + 50855936);
    u16*   srcb = (u16*)(ws + 51904512);
    u16*   acta = (u16*)(ws + 57147392);
    u16*   actb = (u16*)(ws + 61341696);
    float* h1   = (float*)(ws + 57147392);   // overlaps acta; dead before experts
    float* eo   = (float*)(ws + 65536000);
    int*  label = (int*)(ws + 65667072);

    // ---- one-time conversions (re-run each launch; ws is re-poisoned) ----
    convT_k<<<dim3(1024/64, 1280/64, 8), 256, 0, stream>>>(ew1, wT1, 1024, 1280);
    convT_k<<<dim3(1024/64, 1024/64, 8), 256, 0, stream>>>(ew2, wT2, 1024, 1024);
    convT_k<<<dim3( 512/64, 1024/64, 8), 256, 0, stream>>>(ew3, wT3,  512, 1024);
    convT_k<<<dim3(1024/64, 1280/64, 1), 256, 0, stream>>>(dw1, dT1, 1024, 1280);
    convT_k<<<dim3(1024/64, 1024/64, 1), 256, 0, stream>>>(dw2, dT2, 1024, 1024);
    convT_k<<<dim3( 512/64, 1024/64, 1), 256, 0, stream>>>(dw3, dT3,  512, 1024);
    conv_k<<<dim3((B * D / 8 + 255) / 256), 256, 0, stream>>>(src, srcb, B * D / 8);

    // share passthrough (f32 bytes)
    copy16_k<<<dim3((B * D * 4 / 16 + 255) / 256), 256, 0, stream>>>(
        (const uint4*)src, (uint4*)out_share, B * D * 4 / 16);

    // ---- routing: f32-exact h1 GEMM + fused h2/classifier (h1 in acta) ----
    gemm_f32bn_k<<<dim3(512 / 64, B / 64), 256, 0, stream>>>(
        src, bw1, bb1, bg1, bbe1, bm1, bv1, h1, B, 512, D);
    h2cls_k<<<dim3(B), 256, 0, stream>>>(
        h1, bw2, bb2, bg2, bbe2, bm2, bv2, cw, cb, out_src, label);

    // ---- experts, one at a time (pure-bf16 GEMMs, pre-transposed weights) ----
    for (int e = 0; e < E; ++e) {
        gemm_bt_k<0><<<dim3(1024 / 64, B / 64), 256, 0, stream>>>(
            srcb, wT1 + (size_t)e * 1024 * 1280, eb1 + (size_t)e * 1024,
            nullptr, nullptr, nullptr, nullptr, acta, B, 1024, D);
        ln_relu_k<1024><<<dim3(B), 256, 0, stream>>>(
            acta, eg1 + (size_t)e * 1024, ebe1 + (size_t)e * 1024);

        gemm_bt_k<0><<<dim3(1024 / 64, B / 64), 256, 0, stream>>>(
            acta, wT2 + (size_t)e * 1024 * 1024, eb2 + (size_t)e * 1024,
            nullptr, nullptr, nullptr, nullptr, actb, B, 1024, 1024);
        ln_relu_k<1024><<<dim3(B), 256, 0, stream>>>(
            actb, eg2 + (size_t)e * 1024, ebe2 + (size_t)e * 1024);

        gemm_bt_k<0><<<dim3(512 / 64, B / 64), 256, 0, stream>>>(
            actb, wT3 + (size_t)e * 512 * 1024, eb3 + (size_t)e * 512,
            nullptr, nullptr, nullptr, nullptr, acta, B, 512, 1024);
        ln_relu_k<512><<<dim3(B), 256, 0, stream>>>(
            acta, eg3 + (size_t)e * 512, ebe3 + (size_t)e * 512);

        head2_k<<<dim3(B), 64, 0, stream>>>(
            acta, ew4 + (size_t)e * 512 * 2, eb4 + (size_t)e * 2, 512,
            eo + (size_t)e * B * 2);
    }

    gather_k<<<dim3(B / 256), 256, 0, stream>>>(eo, label, out_sout, B);

    // ---- domain classifier (pure-bf16, reuses acta/actb) ----
    gemm_bt_k<1><<<dim3(1024 / 64, B / 64), 256, 0, stream>>>(
        srcb, dT1, db1, dg1, dbe1, dm1, dv1, acta, B, 1024, D);
    gemm_bt_k<1><<<dim3(1024 / 64, B / 64), 256, 0, stream>>>(
        acta, dT2, db2, dg2, dbe2, dm2, dv2, actb, B, 1024, 1024);
    gemm_bt_k<1><<<dim3(512 / 64, B / 64), 256, 0, stream>>>(
        actb, dT3, db3, dg3, dbe3, dm3, dv3, acta, B, 512, 1024);
    head2_k<<<dim3(B), 64, 0, stream>>>(acta, dw4, db4, 512, out_dclf);
}